// Round 8
// baseline (227.936 us; speedup 1.0000x reference)
//
#include <hip/hip_runtime.h>
#include <math.h>

#define BB 8
#define DD 256
#define NN 2048
#define NH 4
#define DH 64

typedef _Float16 half8   __attribute__((ext_vector_type(8)));
typedef _Float16 half4_t __attribute__((ext_vector_type(4)));
typedef _Float16 half2_t __attribute__((ext_vector_type(2)));
typedef float    floatx4 __attribute__((ext_vector_type(4)));

#define MFMA32(A, B, C) __builtin_amdgcn_mfma_f32_16x16x32_f16(A, B, C, 0, 0, 0)
#define MFMA16(A, B, C) __builtin_amdgcn_mfma_f32_16x16x16f16(A, B, C, 0, 0, 0)

// softmax scale folded into Q: 0.125 * log2(e)
#define SC 0.18033688011112042f

// ---------------------------------------------------------------------------
// Weight prep: cast wq/wk/wv to f16 natural [cout][k]; wm permuted k:
// wmf[cout][h*64+d] = wm[cout][4d+h]  (attn-out channel order = h*64+d).
// ---------------------------------------------------------------------------
__global__ __launch_bounds__(256) void prep_weights(
    const float* __restrict__ wq, const float* __restrict__ wk,
    const float* __restrict__ wv, const float* __restrict__ wm,
    _Float16* __restrict__ wqf, _Float16* __restrict__ wkf,
    _Float16* __restrict__ wvf, _Float16* __restrict__ wmf)
{
    int id = blockIdx.x * 256 + threadIdx.x;   // 0..65535
    wqf[id] = (_Float16)wq[id];
    wkf[id] = (_Float16)wk[id];
    wvf[id] = (_Float16)wv[id];
    int row = id >> 8, col = id & 255;
    int hh = col >> 6, dd = col & 63;
    wmf[id] = (_Float16)wm[row * 256 + dd * 4 + hh];
}

// ===========================================================================
// Conv structure: block = 512 thr (8 waves), tile = 256 cout x 32 n, K=256.
// Wave w: cout quarter (w&3)*64, n half (w>>2)*16. X staged once into LDS
// [n 32][k 256] pitch 264; barrier-free k-loop streams weight A-frags from
// global (L2-hot) with 1-deep double buffering.
// ===========================================================================

// k-loop: acc[rt], cout = (w&3)*64 + rt*16 + 4q+r, n = n0 + (w>>2)*16 + c.
#define CONV_KLOOP(Wf)                                                        \
    half8 af[2][4][2];                                                        \
    {                                                                         \
        const _Float16* wp = (Wf) + (size_t)((w & 3) * 64 + c) * 256;         \
        _Pragma("unroll")                                                     \
        for (int rt = 0; rt < 4; ++rt)                                        \
            _Pragma("unroll")                                                 \
            for (int ch = 0; ch < 2; ++ch)                                    \
                af[0][rt][ch] =                                               \
                    *(const half8*)(wp + rt * 16 * 256 + ch * 32 + q * 8);    \
    }                                                                         \
    floatx4 acc[4];                                                           \
    _Pragma("unroll")                                                         \
    for (int rt = 0; rt < 4; ++rt) acc[rt] = (floatx4){0.f, 0.f, 0.f, 0.f};   \
    _Pragma("unroll")                                                         \
    for (int kc = 0; kc < 4; ++kc) {                                          \
        const int cur = kc & 1;                                               \
        if (kc < 3) {                                                         \
            const _Float16* wp = (Wf) + (size_t)((w & 3) * 64 + c) * 256 +    \
                                 (kc + 1) * 64;                               \
            _Pragma("unroll")                                                 \
            for (int rt = 0; rt < 4; ++rt)                                    \
                _Pragma("unroll")                                             \
                for (int ch = 0; ch < 2; ++ch)                                \
                    af[cur ^ 1][rt][ch] = *(const half8*)(wp +                \
                        rt * 16 * 256 + ch * 32 + q * 8);                     \
        }                                                                     \
        _Pragma("unroll")                                                     \
        for (int ch = 0; ch < 2; ++ch) {                                      \
            half8 bx = *(const half8*)(smem + ((w >> 2) * 16 + c) * 264 +     \
                                       kc * 64 + ch * 32 + q * 8);            \
            _Pragma("unroll")                                                 \
            for (int rt = 0; rt < 4; ++rt)                                    \
                acc[rt] = MFMA32(af[cur][rt][ch], bx, acc[rt]);               \
        }                                                                     \
    }

// Stage fp32 X [k][n] -> LDS f16 [n 32][k 256] pitch 264 (4x4 reg transpose).
#define CONV_STAGE_F32(X)                                                     \
    {                                                                         \
        const int nb = t & 7, kb = t >> 3;                                    \
        const float* Xg = (X) + (size_t)b * DD * NN + (size_t)(kb * 4) * NN + \
                          n0 + nb * 4;                                        \
        float4 x[4];                                                          \
        _Pragma("unroll")                                                     \
        for (int i = 0; i < 4; ++i) x[i] = *(const float4*)(Xg + (size_t)i * NN); \
        _Pragma("unroll")                                                     \
        for (int j = 0; j < 4; ++j) {                                         \
            half4_t hv;                                                       \
            _Pragma("unroll")                                                 \
            for (int i = 0; i < 4; ++i)                                       \
                hv[i] = (_Float16)(((const float*)&x[i])[j]);                 \
            *(half4_t*)(smem + (nb * 4 + j) * 264 + kb * 4) = hv;             \
        }                                                                     \
    }                                                                         \
    __syncthreads();

// ---------------------------------------------------------------------------
// Fused Q/K/V projections: blockIdx.z = 0(Q), 1(K), 2(V).
// Q,K out: f16 Y[(b*4+h)*2048+n][d]  (cout = 4d+h; Q scaled by SC)
// V   out: f16 Y[((b*4+h)*64+d)][n]
// grid (64, 8, 3), 512 threads.
// ---------------------------------------------------------------------------
__global__ __launch_bounds__(512, 4) void conv_qkv(
    const _Float16* __restrict__ wqf, const _Float16* __restrict__ wkf,
    const _Float16* __restrict__ wvf,
    const float* __restrict__ bq, const float* __restrict__ bk,
    const float* __restrict__ bv,
    const float* __restrict__ Xq, const float* __restrict__ Xk,
    const float* __restrict__ Xv,
    _Float16* __restrict__ Yq, _Float16* __restrict__ Yk,
    _Float16* __restrict__ Yv)
{
    const int n0 = blockIdx.x * 32;
    const int b  = blockIdx.y;
    const int z  = blockIdx.z;
    const _Float16* Wf = z == 0 ? wqf : (z == 1 ? wkf : wvf);
    const float* bias  = z == 0 ? bq  : (z == 1 ? bk  : bv);
    const float* X     = z == 0 ? Xq  : (z == 1 ? Xk  : Xv);
    const float osc    = z == 0 ? SC : 1.0f;

    const int t = threadIdx.x;
    const int w = t >> 6, l = t & 63, c = l & 15, q = l >> 4;

    __shared__ _Float16 smem[8704];

    CONV_STAGE_F32(X)
    CONV_KLOOP(Wf)

    if (z < 2) {
        // stage [n 32][cout 256] pitch 264, then transpose-gather per (n,h)
        __syncthreads();
        #pragma unroll
        for (int rt = 0; rt < 4; ++rt) {
            half4_t hv;
            #pragma unroll
            for (int r = 0; r < 4; ++r)
                hv[r] = (_Float16)((acc[rt][r] +
                        bias[(w & 3) * 64 + rt * 16 + q * 4 + r]) * osc);
            *(half4_t*)(smem + ((w >> 2) * 16 + c) * 264 +
                        (w & 3) * 64 + rt * 16 + q * 4) = hv;
        }
        __syncthreads();
        _Float16* Y = z == 0 ? Yq : Yk;
        const int pair = t >> 2;              // (n, h)
        const int nn = pair >> 2, hh = pair & 3;
        const int doff = (t & 3) * 16;
        const _Float16* src = smem + nn * 264 + hh;
        half8 hv[2];
        #pragma unroll
        for (int i = 0; i < 2; ++i)
            #pragma unroll
            for (int k = 0; k < 8; ++k)
                hv[i][k] = src[(doff + i * 8 + k) * 4];
        _Float16* dst = Y + ((size_t)(b * NH + hh) * NN + n0 + nn) * 64 + doff;
        *(half8*)dst       = hv[0];
        *(half8*)(dst + 8) = hv[1];
    } else {
        // stage [cout 256][n 32] pitch 34, then row-write
        __syncthreads();
        #pragma unroll
        for (int rt = 0; rt < 4; ++rt)
            #pragma unroll
            for (int r = 0; r < 4; ++r)
                smem[((w & 3) * 64 + rt * 16 + q * 4 + r) * 34 +
                     (w >> 2) * 16 + c] =
                    (_Float16)(acc[rt][r] +
                               bias[(w & 3) * 64 + rt * 16 + q * 4 + r]);
        __syncthreads();
        const int cout = t >> 1, noff = (t & 1) * 16;
        const int hh = cout & 3, dd = cout >> 2;
        _Float16* dst = Yv + ((size_t)(b * NH + hh) * 64 + dd) * NN + n0 + noff;
        *(half8*)dst       = *(const half8*)(smem + cout * 34 + noff);
        *(half8*)(dst + 8) = *(const half8*)(smem + cout * 34 + noff + 8);
    }
}

// ---------------------------------------------------------------------------
// Final projection: X = At f16 [n][256] (copy-staged), output fp32 [b][c][n].
// grid (64, 8), 512 threads.
// ---------------------------------------------------------------------------
__global__ __launch_bounds__(512, 4) void conv_o(
    const _Float16* __restrict__ Wf, const float* __restrict__ bias,
    const _Float16* __restrict__ At, float* __restrict__ out)
{
    const int n0 = blockIdx.x * 32;
    const int b  = blockIdx.y;
    const int t  = threadIdx.x;
    const int w  = t >> 6, l = t & 63, c = l & 15, q = l >> 4;

    __shared__ _Float16 smem[8704];

    {
        const int row = t >> 4, seg = (t & 15) * 16;   // 32 rows x 256 halves
        const _Float16* Xg = At + ((size_t)b * NN + n0 + row) * 256 + seg;
        *(half8*)(smem + row * 264 + seg)     = *(const half8*)(Xg);
        *(half8*)(smem + row * 264 + seg + 8) = *(const half8*)(Xg + 8);
    }
    __syncthreads();

    CONV_KLOOP(Wf)

    // fp32 epilogue via LDS float pitch 34, 2 passes of 128 couts
    float* fs = (float*)smem;
    #pragma unroll
    for (int p = 0; p < 2; ++p) {
        __syncthreads();
        if (((w & 3) >> 1) == p) {
            const int cl = ((w & 3) & 1) * 64;
            #pragma unroll
            for (int rt = 0; rt < 4; ++rt)
                #pragma unroll
                for (int r = 0; r < 4; ++r)
                    fs[(cl + rt * 16 + q * 4 + r) * 34 + (w >> 2) * 16 + c] =
                        acc[rt][r] + bias[(w & 3) * 64 + rt * 16 + q * 4 + r];
        }
        __syncthreads();
        const int row = t >> 2, noff = (t & 3) * 8;
        float* dst = out + (size_t)b * DD * NN +
                     (size_t)(p * 128 + row) * NN + n0 + noff;
        *(float4*)dst       = *(const float4*)(fs + row * 34 + noff);
        *(float4*)(dst + 4) = *(const float4*)(fs + row * 34 + noff + 4);
    }
}

// ---------------------------------------------------------------------------
// MFMA flash attention. 512 thr = 8 waves x 16 q-cols; q-tile 128; BM = 128.
// Register double-buffered K/V staging: next tile's global loads issue before
// current tile's compute, so the vmcnt wait lands after the MFMA block.
// S^T = K^T Q (16x16x32); exp(S^T) C-frags are directly 16x16x16 B-frags for
// PV.  V sigma-permuted in LDS (one b128 read = A-frags for two 16-m tiles).
// grid (16, 4, 8), LDS = Ks[128][72] + Vs[64][136] = 35.8 KB.
// ---------------------------------------------------------------------------
__global__ __launch_bounds__(512) void attn_mfma5(
    const _Float16* __restrict__ Qt, const _Float16* __restrict__ Kt,
    const _Float16* __restrict__ V, _Float16* __restrict__ At)
{
    const int n0 = blockIdx.x * 128;
    const int h  = blockIdx.y;
    const int b  = blockIdx.z;
    const int t  = threadIdx.x;
    const int w  = t >> 6, l = t & 63, c = l & 15, q = l >> 4;

    const size_t bh = (size_t)(b * NH + h);

    __shared__ _Float16 smem[9216 + 8704];
    _Float16* Ks = smem;            // [m 128][d 64] pitch 72
    _Float16* Vs = smem + 9216;     // [d 64][sigma(m) 128] pitch 136

    half8 bq2[2];
    #pragma unroll
    for (int ch = 0; ch < 2; ++ch)
        bq2[ch] = *(const half8*)(Qt + (bh * NN + n0 + w * 16 + c) * 64 + ch * 32 + q * 8);

    float lp = 0.f;
    floatx4 o[4];
    #pragma unroll
    for (int dt = 0; dt < 4; ++dt) o[dt] = (floatx4){0.f, 0.f, 0.f, 0.f};

    const int ksr = t >> 2, ksc = (t & 3) * 16;   // K staging: 128 rows
    const int vr  = t >> 3, vcb = (t & 7) * 16;   // V staging: 64 rows, 16 m
    const _Float16* Kg = Kt + bh * NN * 64;       // [m][d]
    const _Float16* Vg = V + bh * 64 * NN;        // [d][n]

    half8 kpre[2], vpre[2];
    kpre[0] = *(const half8*)(Kg + (size_t)ksr * 64 + ksc);
    kpre[1] = *(const half8*)(Kg + (size_t)ksr * 64 + ksc + 8);
    vpre[0] = *(const half8*)(Vg + (size_t)vr * NN + vcb);
    vpre[1] = *(const half8*)(Vg + (size_t)vr * NN + vcb + 8);

    for (int m0 = 0; m0 < NN; m0 += 128) {
        __syncthreads();
        *(half8*)(Ks + ksr * 72 + ksc)     = kpre[0];
        *(half8*)(Ks + ksr * 72 + ksc + 8) = kpre[1];
        #pragma unroll
        for (int u = 0; u < 2; ++u) {
            const int mb = vcb + u * 8;
            const int p0 = (mb & ~31) + (((mb >> 2) & 3) << 3) + (((mb >> 4) & 1) << 2);
            half4_t lo, hi;
            #pragma unroll
            for (int j = 0; j < 4; ++j) { lo[j] = vpre[u][j]; hi[j] = vpre[u][4 + j]; }
            *(half4_t*)(Vs + vr * 136 + p0)     = lo;
            *(half4_t*)(Vs + vr * 136 + p0 + 8) = hi;
        }
        __syncthreads();

        // prefetch next tile into regs (clamped on last iter; no wait here)
        const int mn = (m0 + 128 < NN) ? m0 + 128 : m0;
        kpre[0] = *(const half8*)(Kg + (size_t)(mn + ksr) * 64 + ksc);
        kpre[1] = *(const half8*)(Kg + (size_t)(mn + ksr) * 64 + ksc + 8);
        vpre[0] = *(const half8*)(Vg + (size_t)vr * NN + mn + vcb);
        vpre[1] = *(const half8*)(Vg + (size_t)vr * NN + mn + vcb + 8);

        #pragma unroll
        for (int mt2 = 0; mt2 < 4; ++mt2) {
            half4_t p[2];
            #pragma unroll
            for (int hf = 0; hf < 2; ++hf) {
                const int mt = mt2 * 2 + hf;
                floatx4 s = {0.f, 0.f, 0.f, 0.f};
                #pragma unroll
                for (int ch = 0; ch < 2; ++ch) {
                    half8 ak = *(const half8*)(Ks + (mt * 16 + c) * 72 + ch * 32 + q * 8);
                    s = MFMA32(ak, bq2[ch], s);
                }
                float e0 = exp2f(s[0]), e1 = exp2f(s[1]);
                float e2 = exp2f(s[2]), e3 = exp2f(s[3]);
                lp += (e0 + e1) + (e2 + e3);
                half2_t c01 = __builtin_bit_cast(half2_t, __builtin_amdgcn_cvt_pkrtz(e0, e1));
                half2_t c23 = __builtin_bit_cast(half2_t, __builtin_amdgcn_cvt_pkrtz(e2, e3));
                p[hf][0] = c01[0]; p[hf][1] = c01[1];
                p[hf][2] = c23[0]; p[hf][3] = c23[1];
            }
            #pragma unroll
            for (int dt = 0; dt < 4; ++dt) {
                half8 av = *(const half8*)(Vs + (dt * 16 + c) * 136 + mt2 * 32 + q * 8);
                half4_t alo, ahi;
                #pragma unroll
                for (int j = 0; j < 4; ++j) { alo[j] = av[j]; ahi[j] = av[4 + j]; }
                o[dt] = MFMA16(alo, p[0], o[dt]);
                o[dt] = MFMA16(ahi, p[1], o[dt]);
            }
        }
    }

    lp += __shfl_xor(lp, 16);
    lp += __shfl_xor(lp, 32);
    const float inv = 1.f / lp;

    __syncthreads();
    #pragma unroll
    for (int dt = 0; dt < 4; ++dt) {
        half4_t ov;
        #pragma unroll
        for (int r = 0; r < 4; ++r) ov[r] = (_Float16)(o[dt][r] * inv);
        *(half4_t*)(smem + (w * 16 + c) * 72 + dt * 16 + q * 4) = ov;
    }
    __syncthreads();

    const int rn = t >> 2, roff = (t & 3) * 16;
    _Float16* dst = At + ((size_t)b * NN + n0 + rn) * 256 + h * 64 + roff;
    *(half8*)dst       = *(const half8*)(smem + rn * 72 + roff);
    *(half8*)(dst + 8) = *(const half8*)(smem + rn * 72 + roff + 8);
}

extern "C" void kernel_launch(void* const* d_in, const int* in_sizes, int n_in,
                              void* d_out, int out_size, void* d_ws, size_t ws_size,
                              hipStream_t stream) {
    const float* query = (const float*)d_in[0];
    const float* key_  = (const float*)d_in[1];
    const float* value = (const float*)d_in[2];
    const float* wq    = (const float*)d_in[3];
    const float* bq    = (const float*)d_in[4];
    const float* wk    = (const float*)d_in[5];
    const float* bk    = (const float*)d_in[6];
    const float* wv    = (const float*)d_in[7];
    const float* bv    = (const float*)d_in[8];
    const float* wm    = (const float*)d_in[9];
    const float* bm    = (const float*)d_in[10];
    float* out = (float*)d_out;

    _Float16* ws = (_Float16*)d_ws;
    _Float16* wqf = ws;
    _Float16* wkf = wqf + 65536;
    _Float16* wvf = wkf + 65536;
    _Float16* wmf = wvf + 65536;
    const size_t e16 = (size_t)BB * NH * NN * DH;   // 4,194,304
    _Float16* qf = ws + 262144;
    _Float16* kf = qf + e16;
    _Float16* vf = kf + e16;
    _Float16* at = vf + e16;

    prep_weights<<<256, 256, 0, stream>>>(wq, wk, wv, wm, wqf, wkf, wvf, wmf);
    conv_qkv<<<dim3(64, 8, 3), 512, 0, stream>>>(wqf, wkf, wvf, bq, bk, bv,
                                                 query, key_, value, qf, kf, vf);
    attn_mfma5<<<dim3(16, 4, 8), 512, 0, stream>>>(qf, kf, vf, at);
    conv_o<<<dim3(64, 8), 512, 0, stream>>>(wmf, bm, at, out);
}

// Round 9
// 211.284 us; speedup vs baseline: 1.0788x; 1.0788x over previous
//
#include <hip/hip_runtime.h>
#include <math.h>

#define BB 8
#define DD 256
#define NN 2048
#define NH 4
#define DH 64

typedef _Float16 half8   __attribute__((ext_vector_type(8)));
typedef _Float16 half4_t __attribute__((ext_vector_type(4)));
typedef _Float16 half2_t __attribute__((ext_vector_type(2)));
typedef float    floatx4 __attribute__((ext_vector_type(4)));

#define MFMA32(A, B, C) __builtin_amdgcn_mfma_f32_16x16x32_f16(A, B, C, 0, 0, 0)

// softmax scale folded into Q: 0.125 * log2(e)
#define SC 0.18033688011112042f

// ---------------------------------------------------------------------------
// Weight prep: cast wq/wk/wv to f16 natural [cout][k]; wm permuted k:
// wmf[cout][h*64+d] = wm[cout][4d+h]  (attn-out channel order = h*64+d).
// ---------------------------------------------------------------------------
__global__ __launch_bounds__(256) void prep_weights(
    const float* __restrict__ wq, const float* __restrict__ wk,
    const float* __restrict__ wv, const float* __restrict__ wm,
    _Float16* __restrict__ wqf, _Float16* __restrict__ wkf,
    _Float16* __restrict__ wvf, _Float16* __restrict__ wmf)
{
    int id = blockIdx.x * 256 + threadIdx.x;   // 0..65535
    wqf[id] = (_Float16)wq[id];
    wkf[id] = (_Float16)wk[id];
    wvf[id] = (_Float16)wv[id];
    int row = id >> 8, col = id & 255;
    int hh = col >> 6, dd = col & 63;
    wmf[id] = (_Float16)wm[row * 256 + dd * 4 + hh];
}

// ===========================================================================
// Conv: weights-in-registers. Block 256 thr (4 waves), tile 128 cout x 64 n,
// K = 256. Wave w holds its 32-cout x 256-k W slice as A-frags in 64 VGPRs
// (loaded once). X staged once to LDS [n 64][k 256] pitch 264; k-loop is
// barrier-free and has NO global loads: 8 ds_read_b128 x 4 nt -> 64 MFMA.
// ===========================================================================

// ---------------------------------------------------------------------------
// Fused Q/K/V projections. grid (32, 8, 6): z = tensor*2 + cout-half.
// Q,K out: f16 Y[(b*4+h)*2048+n][d]  (cout = 4d+h; Q scaled by SC)
// V   out: f16 Y[((b*4+h)*64+d)][n]
// ---------------------------------------------------------------------------
__global__ __launch_bounds__(256, 3) void conv_qkv(
    const _Float16* __restrict__ wqf, const _Float16* __restrict__ wkf,
    const _Float16* __restrict__ wvf,
    const float* __restrict__ bq, const float* __restrict__ bk,
    const float* __restrict__ bv,
    const float* __restrict__ Xq, const float* __restrict__ Xk,
    const float* __restrict__ Xv,
    _Float16* __restrict__ Yq, _Float16* __restrict__ Yk,
    _Float16* __restrict__ Yv)
{
    const int n0 = blockIdx.x * 64;
    const int b  = blockIdx.y;
    const int zh = blockIdx.z;
    const int z  = zh >> 1;
    const int hf = zh & 1;          // cout half
    const _Float16* Wf = z == 0 ? wqf : (z == 1 ? wkf : wvf);
    const float* bias  = z == 0 ? bq  : (z == 1 ? bk  : bv);
    const float* X     = z == 0 ? Xq  : (z == 1 ? Xk  : Xv);
    const float osc    = z == 0 ? SC : 1.0f;
    const int cout0 = hf * 128;

    const int t = threadIdx.x;
    const int w = t >> 6, l = t & 63, c = l & 15, q = l >> 4;

    __shared__ _Float16 smem[64 * 264];   // 33.8 KB

    // weight A-frags, loaded once: wave w owns couts cout0 + w*32 .. +32
    half8 af[2][8];
    {
        const _Float16* wp = Wf + (size_t)(cout0 + w * 32 + c) * 256 + q * 8;
        #pragma unroll
        for (int rt = 0; rt < 2; ++rt)
            #pragma unroll
            for (int ch = 0; ch < 8; ++ch)
                af[rt][ch] = *(const half8*)(wp + rt * 16 * 256 + ch * 32);
    }

    // stage X fp32 [k][n] -> LDS f16 [n][k], 4 chunks of 64 k
    {
        const int nb = t & 15, kb = t >> 4;
        #pragma unroll
        for (int cc = 0; cc < 4; ++cc) {
            const float* Xg = X + (size_t)b * DD * NN +
                              (size_t)(cc * 64 + kb * 4) * NN + n0 + nb * 4;
            float4 x[4];
            #pragma unroll
            for (int i = 0; i < 4; ++i) x[i] = *(const float4*)(Xg + (size_t)i * NN);
            #pragma unroll
            for (int j = 0; j < 4; ++j) {
                half4_t hv;
                #pragma unroll
                for (int i = 0; i < 4; ++i) hv[i] = (_Float16)(((const float*)&x[i])[j]);
                *(half4_t*)(smem + (nb * 4 + j) * 264 + cc * 64 + kb * 4) = hv;
            }
        }
    }
    __syncthreads();

    floatx4 acc[2][4];
    #pragma unroll
    for (int rt = 0; rt < 2; ++rt)
        #pragma unroll
        for (int nt = 0; nt < 4; ++nt) acc[rt][nt] = (floatx4){0.f, 0.f, 0.f, 0.f};

    #pragma unroll
    for (int ch = 0; ch < 8; ++ch)
        #pragma unroll
        for (int nt = 0; nt < 4; ++nt) {
            half8 bx = *(const half8*)(smem + (nt * 16 + c) * 264 + ch * 32 + q * 8);
            acc[0][nt] = MFMA32(af[0][ch], bx, acc[0][nt]);
            acc[1][nt] = MFMA32(af[1][ch], bx, acc[1][nt]);
        }

    if (z < 2) {
        // stage [n 64][cl 128] pitch 136, gather 32-d runs per (n, h)
        __syncthreads();
        #pragma unroll
        for (int rt = 0; rt < 2; ++rt)
            #pragma unroll
            for (int nt = 0; nt < 4; ++nt) {
                half4_t hv;
                #pragma unroll
                for (int r = 0; r < 4; ++r)
                    hv[r] = (_Float16)((acc[rt][nt][r] +
                            bias[cout0 + w * 32 + rt * 16 + q * 4 + r]) * osc);
                *(half4_t*)(smem + (nt * 16 + c) * 136 + w * 32 + rt * 16 + q * 4) = hv;
            }
        __syncthreads();
        _Float16* Y = z == 0 ? Yq : Yk;
        const int nn = t >> 2, hh = t & 3;
        half8 hv[4];
        #pragma unroll
        for (int i = 0; i < 4; ++i)
            #pragma unroll
            for (int k = 0; k < 8; ++k)
                hv[i][k] = smem[nn * 136 + (i * 8 + k) * 4 + hh];
        _Float16* dst = Y + ((size_t)(b * NH + hh) * NN + n0 + nn) * 64 + hf * 32;
        #pragma unroll
        for (int i = 0; i < 4; ++i) *(half8*)(dst + i * 8) = hv[i];
    } else {
        // stage [cl 128][n 64] pitch 72, row-write per cout
        __syncthreads();
        #pragma unroll
        for (int rt = 0; rt < 2; ++rt)
            #pragma unroll
            for (int nt = 0; nt < 4; ++nt)
                #pragma unroll
                for (int r = 0; r < 4; ++r)
                    smem[(w * 32 + rt * 16 + q * 4 + r) * 72 + nt * 16 + c] =
                        (_Float16)(acc[rt][nt][r] +
                                   bias[cout0 + w * 32 + rt * 16 + q * 4 + r]);
        __syncthreads();
        const int cl = t >> 1, noff = (t & 1) * 32;
        const int cout = cout0 + cl;
        const int hh = cout & 3, dd = cout >> 2;
        _Float16* dst = Yv + ((size_t)(b * NH + hh) * 64 + dd) * NN + n0 + noff;
        #pragma unroll
        for (int i = 0; i < 4; ++i)
            *(half8*)(dst + i * 8) = *(const half8*)(smem + cl * 72 + noff + i * 8);
    }
}

// ---------------------------------------------------------------------------
// Final projection: weights in regs, B-frags DIRECT from global At[n][256]
// (natural half8s, no LDS staging). Output fp32 [b][cout][n].
// grid (32, 8, 2): z = cout half.
// ---------------------------------------------------------------------------
__global__ __launch_bounds__(256, 3) void conv_o(
    const _Float16* __restrict__ Wf, const float* __restrict__ bias,
    const _Float16* __restrict__ At, float* __restrict__ out)
{
    const int n0 = blockIdx.x * 64;
    const int b  = blockIdx.y;
    const int hf = blockIdx.z;
    const int cout0 = hf * 128;

    const int t = threadIdx.x;
    const int w = t >> 6, l = t & 63, c = l & 15, q = l >> 4;

    __shared__ float fs[128 * 66];   // 33.8 KB

    half8 af[2][8];
    {
        const _Float16* wp = Wf + (size_t)(cout0 + w * 32 + c) * 256 + q * 8;
        #pragma unroll
        for (int rt = 0; rt < 2; ++rt)
            #pragma unroll
            for (int ch = 0; ch < 8; ++ch)
                af[rt][ch] = *(const half8*)(wp + rt * 16 * 256 + ch * 32);
    }

    floatx4 acc[2][4];
    #pragma unroll
    for (int rt = 0; rt < 2; ++rt)
        #pragma unroll
        for (int nt = 0; nt < 4; ++nt) acc[rt][nt] = (floatx4){0.f, 0.f, 0.f, 0.f};

    #pragma unroll
    for (int ch = 0; ch < 8; ++ch)
        #pragma unroll
        for (int nt = 0; nt < 4; ++nt) {
            half8 bx = *(const half8*)(At +
                ((size_t)b * NN + n0 + nt * 16 + c) * 256 + ch * 32 + q * 8);
            acc[0][nt] = MFMA32(af[0][ch], bx, acc[0][nt]);
            acc[1][nt] = MFMA32(af[1][ch], bx, acc[1][nt]);
        }

    #pragma unroll
    for (int rt = 0; rt < 2; ++rt)
        #pragma unroll
        for (int nt = 0; nt < 4; ++nt)
            #pragma unroll
            for (int r = 0; r < 4; ++r)
                fs[(w * 32 + rt * 16 + q * 4 + r) * 66 + nt * 16 + c] =
                    acc[rt][nt][r] + bias[cout0 + w * 32 + rt * 16 + q * 4 + r];
    __syncthreads();
    const int cl = t >> 1, noff = (t & 1) * 32;
    float* dst = out + (size_t)b * DD * NN + (size_t)(cout0 + cl) * NN + n0 + noff;
    #pragma unroll
    for (int i = 0; i < 8; ++i)
        *(float4*)(dst + i * 4) = *(const float4*)(fs + cl * 66 + noff + i * 4);
}

// ---------------------------------------------------------------------------
// MFMA flash attention, 2-way m-split. 512 thr = 8 waves x 16 q-cols; q-tile
// 128; BM = 128; block handles m in [part*1024, part*1024+1024).
// S^T = K^T Q (16x16x32). PV upgraded to ONE 16x16x32 MFMA per (dt, mt2):
// the sigma-permuted V column order kappa(m) = 32(m>>5)+8((m>>2)&3)+
// 4((m>>4)&1)+(m&3) makes av a valid A-frag for k=q*8+j, and B = concat(p0,p1).
// Partial outputs: Op f32 [part][b][n][h*64+d], Lp f32 [part][b][h][n].
// grid (16, 4, 16): z = b*2 + part -> 1024 blocks = 4 blocks/CU.
// ---------------------------------------------------------------------------
__global__ __launch_bounds__(512) void attn_mfma6(
    const _Float16* __restrict__ Qt, const _Float16* __restrict__ Kt,
    const _Float16* __restrict__ V, float* __restrict__ Op,
    float* __restrict__ Lp)
{
    const int n0 = blockIdx.x * 128;
    const int h  = blockIdx.y;
    const int bp = blockIdx.z;
    const int b  = bp >> 1, part = bp & 1;
    const int t  = threadIdx.x;
    const int w  = t >> 6, l = t & 63, c = l & 15, q = l >> 4;

    const size_t bh = (size_t)(b * NH + h);
    const int m_start = part * 1024, m_end = m_start + 1024;

    __shared__ _Float16 smem[9216 + 8704];   // 35.8 KB
    _Float16* Ks = smem;            // [m 128][d 64] pitch 72
    _Float16* Vs = smem + 9216;     // [d 64][kappa(m) 128] pitch 136

    half8 bq2[2];
    #pragma unroll
    for (int ch = 0; ch < 2; ++ch)
        bq2[ch] = *(const half8*)(Qt + (bh * NN + n0 + w * 16 + c) * 64 + ch * 32 + q * 8);

    float lp = 0.f;
    floatx4 o[4];
    #pragma unroll
    for (int dt = 0; dt < 4; ++dt) o[dt] = (floatx4){0.f, 0.f, 0.f, 0.f};

    const int ksr = t >> 2, ksc = (t & 3) * 16;
    const int vr  = t >> 3, vcb = (t & 7) * 16;
    const _Float16* Kg = Kt + bh * NN * 64;   // [m][d]
    const _Float16* Vg = V + bh * 64 * NN;    // [d][n]

    half8 kpre[2], vpre[2];
    kpre[0] = *(const half8*)(Kg + (size_t)(m_start + ksr) * 64 + ksc);
    kpre[1] = *(const half8*)(Kg + (size_t)(m_start + ksr) * 64 + ksc + 8);
    vpre[0] = *(const half8*)(Vg + (size_t)vr * NN + m_start + vcb);
    vpre[1] = *(const half8*)(Vg + (size_t)vr * NN + m_start + vcb + 8);

    for (int m0 = m_start; m0 < m_end; m0 += 128) {
        __syncthreads();
        *(half8*)(Ks + ksr * 72 + ksc)     = kpre[0];
        *(half8*)(Ks + ksr * 72 + ksc + 8) = kpre[1];
        #pragma unroll
        for (int u = 0; u < 2; ++u) {
            const int mb = vcb + u * 8;
            const int p0 = (mb & ~31) + (((mb >> 2) & 3) << 3) + (((mb >> 4) & 1) << 2);
            half4_t lo, hi;
            #pragma unroll
            for (int j = 0; j < 4; ++j) { lo[j] = vpre[u][j]; hi[j] = vpre[u][4 + j]; }
            *(half4_t*)(Vs + vr * 136 + p0)     = lo;
            *(half4_t*)(Vs + vr * 136 + p0 + 8) = hi;
        }
        __syncthreads();

        const int mn = (m0 + 128 < m_end) ? m0 + 128 : m0;
        kpre[0] = *(const half8*)(Kg + (size_t)(mn + ksr) * 64 + ksc);
        kpre[1] = *(const half8*)(Kg + (size_t)(mn + ksr) * 64 + ksc + 8);
        vpre[0] = *(const half8*)(Vg + (size_t)vr * NN + mn + vcb);
        vpre[1] = *(const half8*)(Vg + (size_t)vr * NN + mn + vcb + 8);

        #pragma unroll
        for (int mt2 = 0; mt2 < 4; ++mt2) {
            half8 p8;
            #pragma unroll
            for (int hfm = 0; hfm < 2; ++hfm) {
                const int mt = mt2 * 2 + hfm;
                floatx4 s = {0.f, 0.f, 0.f, 0.f};
                #pragma unroll
                for (int ch = 0; ch < 2; ++ch) {
                    half8 ak = *(const half8*)(Ks + (mt * 16 + c) * 72 + ch * 32 + q * 8);
                    s = MFMA32(ak, bq2[ch], s);
                }
                float e0 = exp2f(s[0]), e1 = exp2f(s[1]);
                float e2 = exp2f(s[2]), e3 = exp2f(s[3]);
                lp += (e0 + e1) + (e2 + e3);
                half2_t c01 = __builtin_bit_cast(half2_t, __builtin_amdgcn_cvt_pkrtz(e0, e1));
                half2_t c23 = __builtin_bit_cast(half2_t, __builtin_amdgcn_cvt_pkrtz(e2, e3));
                p8[hfm * 4 + 0] = c01[0]; p8[hfm * 4 + 1] = c01[1];
                p8[hfm * 4 + 2] = c23[0]; p8[hfm * 4 + 3] = c23[1];
            }
            #pragma unroll
            for (int dt = 0; dt < 4; ++dt) {
                half8 av = *(const half8*)(Vs + (dt * 16 + c) * 136 + mt2 * 32 + q * 8);
                o[dt] = MFMA32(av, p8, o[dt]);
            }
        }
    }

    lp += __shfl_xor(lp, 16);
    lp += __shfl_xor(lp, 32);
    if (l < 16)
        Lp[((size_t)(part * 8 + b) * NH + h) * NN + n0 + w * 16 + c] = lp;

    // stage raw O (f32) and write partials: Op[part][b][n][h*64+d]
    __syncthreads();
    float* fsm = (float*)smem;       // [n 128][d 64] pitch 68
    #pragma unroll
    for (int dt = 0; dt < 4; ++dt)
        #pragma unroll
        for (int r = 0; r < 4; ++r)
            fsm[(w * 16 + c) * 68 + dt * 16 + q * 4 + r] = o[dt][r];
    __syncthreads();
    const int rn = t >> 2, seg = (t & 3) * 16;
    float* dst = Op + ((size_t)(part * 8 + b) * NN + n0 + rn) * 256 + h * 64 + seg;
    #pragma unroll
    for (int i = 0; i < 4; ++i)
        *(float4*)(dst + i * 4) = *(const float4*)(fsm + rn * 68 + seg + i * 4);
}

// ---------------------------------------------------------------------------
// Combine the two m-partials: At[b][n][hd] = (Op0+Op1) / (l0+l1), f16.
// grid (2048), 256 thr; each thread does 8 elements (one h-aligned run).
// ---------------------------------------------------------------------------
__global__ __launch_bounds__(256) void attn_combine(
    const float* __restrict__ Op, const float* __restrict__ Lp,
    _Float16* __restrict__ At)
{
    const size_t base = ((size_t)blockIdx.x * 256 + threadIdx.x) * 8;
    const int b  = (int)(base >> 19);          // 2048*256 per batch
    const int rem = (int)(base & 524287);
    const int n  = rem >> 8;
    const int hh = (rem & 255) >> 6;
    const float l0 = Lp[((size_t)b * NH + hh) * NN + n];
    const float l1 = Lp[((size_t)(8 + b) * NH + hh) * NN + n];
    const float inv = 1.f / (l0 + l1);
    const float* p0 = Op + base;
    const float* p1 = Op + base + (size_t)8 * NN * 256;
    half8 hv;
    #pragma unroll
    for (int i = 0; i < 8; ++i)
        hv[i] = (_Float16)((p0[i] + p1[i]) * inv);
    *(half8*)(At + base) = hv;
}

extern "C" void kernel_launch(void* const* d_in, const int* in_sizes, int n_in,
                              void* d_out, int out_size, void* d_ws, size_t ws_size,
                              hipStream_t stream) {
    const float* query = (const float*)d_in[0];
    const float* key_  = (const float*)d_in[1];
    const float* value = (const float*)d_in[2];
    const float* wq    = (const float*)d_in[3];
    const float* bq    = (const float*)d_in[4];
    const float* wk    = (const float*)d_in[5];
    const float* bk    = (const float*)d_in[6];
    const float* wv    = (const float*)d_in[7];
    const float* bv    = (const float*)d_in[8];
    const float* wm    = (const float*)d_in[9];
    const float* bm    = (const float*)d_in[10];
    float* out = (float*)d_out;

    _Float16* ws = (_Float16*)d_ws;
    _Float16* wqf = ws;
    _Float16* wkf = wqf + 65536;
    _Float16* wvf = wkf + 65536;
    _Float16* wmf = wvf + 65536;
    const size_t e16 = (size_t)BB * NH * NN * DH;   // 4,194,304
    _Float16* qf = ws + 262144;
    _Float16* kf = qf + e16;
    _Float16* vf = kf + e16;
    float*    Op = (float*)(vf + e16);              // 2 x 8.4M f32 = 33.6 MB
    float*    Lp = Op + 2 * e16;                    // 131072 f32
    _Float16* at = qf;                              // overlay (qf dead post-attn)

    prep_weights<<<256, 256, 0, stream>>>(wq, wk, wv, wm, wqf, wkf, wvf, wmf);
    conv_qkv<<<dim3(32, 8, 6), 256, 0, stream>>>(wqf, wkf, wvf, bq, bk, bv,
                                                 query, key_, value, qf, kf, vf);
    attn_mfma6<<<dim3(16, 4, 16), 512, 0, stream>>>(qf, kf, vf, Op, Lp);
    attn_combine<<<2048, 256, 0, stream>>>(Op, Lp, at);
    conv_o<<<dim3(32, 8, 2), 256, 0, stream>>>(wmf, bm, at, out);
}